// Round 1
// baseline (716.500 us; speedup 1.0000x reference)
//
#include <hip/hip_runtime.h>
#include <math.h>

#define NN 1024

__device__ __forceinline__ float wave_sum(float v) {
#pragma unroll
  for (int off = 32; off > 0; off >>= 1) v += __shfl_down(v, off);
  return v;
}
__device__ __forceinline__ float wave_max(float v) {
#pragma unroll
  for (int off = 32; off > 0; off >>= 1) v = fmaxf(v, __shfl_down(v, off));
  return v;
}

#define SH_C0 0.28209479177387814f
#define SH_C1 0.4886025119029199f
#define SH_S15 1.0925484305920792f
#define SH_S5 0.6307831305050401f

// ---------------------------------------------------------------------------
// K0: transpose the 8 [128x128] weight matrices so GEMV reads are coalesced.
// slot 0: q_w^T, 1: k_w^T, 2..4: v_w[l]^T, 5..7: out_w[l]^T
__global__ __launch_bounds__(256) void htr_transpose(
    const float* __restrict__ qw, const float* __restrict__ kw,
    const float* __restrict__ vw, const float* __restrict__ ow,
    float* __restrict__ wT) {
  const int b = blockIdx.x;  // 0..7
  const float* src;
  if (b == 0) src = qw;
  else if (b == 1) src = kw;
  else if (b < 5) src = vw + (b - 2) * 16384;
  else src = ow + (b - 5) * 16384;
  float* dst = wT + b * 16384;
  for (int idx = threadIdx.x; idx < 16384; idx += 256) {
    int r = idx >> 7, cc = idx & 127;
    dst[cc * 128 + r] = src[idx];
  }
}

// ---------------------------------------------------------------------------
// K1: S_row[i][m] = (1/N) sum_j valid(i,j) * sh_m(r_hat(i,j))
__global__ __launch_bounds__(256) void htr_row_stats(
    const float* __restrict__ pos, const int* __restrict__ batch,
    float* __restrict__ S_row) {
  const int i = blockIdx.x;
  const int tid = threadIdx.x;
  const float px = pos[i * 3 + 0], py = pos[i * 3 + 1], pz = pos[i * 3 + 2];
  const int bi = batch[i];
  float s[9];
#pragma unroll
  for (int m = 0; m < 9; ++m) s[m] = 0.f;
  for (int j = tid; j < NN; j += 256) {
    if (j == i) continue;
    if (batch[j] != bi) continue;
    float dx = px - pos[j * 3 + 0];
    float dy = py - pos[j * 3 + 1];
    float dz = pz - pos[j * 3 + 2];
    float d2 = dx * dx + dy * dy + dz * dz;
    float dist = fmaxf(sqrtf(d2), 1e-8f);
    float inv = 1.0f / dist;
    float x = dx * inv, y = dy * inv, z = dz * inv;
    s[0] += 1.0f;
    s[1] += x; s[2] += y; s[3] += z;
    s[4] += x * z; s[5] += x * y;
    s[6] += y * y - 0.5f * (x * x + z * z);
    s[7] += y * z;
    s[8] += z * z - x * x;
  }
  __shared__ float red[4][9];
  const int wave = tid >> 6, lane = tid & 63;
#pragma unroll
  for (int m = 0; m < 9; ++m) {
    float v = wave_sum(s[m]);
    if (lane == 0) red[wave][m] = v;
  }
  __syncthreads();
  if (tid < 9) {
    float v = red[0][tid] + red[1][tid] + red[2][tid] + red[3][tid];
    float scl = SH_S15;
    if (tid == 0) scl = SH_C0;
    else if (tid < 4) scl = SH_C1;
    else if (tid == 6) scl = SH_S5;
    else if (tid == 8) scl = 0.5f * SH_S15;
    S_row[i * 9 + tid] = v * scl * (1.0f / 1024.0f);
  }
}

// ---------------------------------------------------------------------------
// K2: rowmean[i,c] = sum_m S_row[i,m] * invdeg(m) * x_emb[i,m,c]
__global__ __launch_bounds__(128) void htr_rowmean(
    const float* __restrict__ x_emb, const float* __restrict__ S_row,
    float* __restrict__ rowm) {
  const int i = blockIdx.x;
  const int c = threadIdx.x;
  float acc = 0.f;
#pragma unroll
  for (int m = 0; m < 9; ++m) {
    float idg = (m == 0) ? 1.f : ((m < 4) ? (1.f / 3.f) : 0.2f);
    acc = fmaf(S_row[i * 9 + m] * idg, x_emb[(i * 9 + m) * 128 + c], acc);
  }
  rowm[i * 128 + c] = acc;
}

// ---------------------------------------------------------------------------
// K3: colmean[j,c] = (1/N) sum_i valid(i,j) sum_m sh_m(r_hat(i,j)) f'[i,m,c]
// block: 4 j's, 256 threads = (jp in 0..1 handling 2 j's) x (c in 0..127).
// i staged in tiles of 8 into LDS (f' = x_emb * invdeg); per-pair sh computed
// once by 32 threads into LDS.
__global__ __launch_bounds__(256) void htr_colmean(
    const float* __restrict__ x_emb, const float* __restrict__ pos,
    const int* __restrict__ batch, float* __restrict__ colm) {
  const int jbase = blockIdx.x * 4;
  const int tid = threadIdx.x;
  const int jp = tid >> 7;   // 0..1
  const int c = tid & 127;
  __shared__ float fs[8][9][128];   // 36 KB
  __shared__ float wsm[8][9][4];    // [ii][m][tj]
  __shared__ float pj[4][3];
  __shared__ int bj[4];
  if (tid < 4) {
    int j = jbase + tid;
    pj[tid][0] = pos[j * 3 + 0];
    pj[tid][1] = pos[j * 3 + 1];
    pj[tid][2] = pos[j * 3 + 2];
    bj[tid] = batch[j];
  }
  __syncthreads();
  float acc0 = 0.f, acc1 = 0.f;
  for (int i0 = 0; i0 < 1024; i0 += 8) {
    const float4* src = (const float4*)(x_emb + i0 * 1152);
    float4* dst = (float4*)(&fs[0][0][0]);
#pragma unroll
    for (int it = 0; it < 9; ++it) {
      int idx4 = tid + it * 256;       // 2304 float4 total
      float4 v = src[idx4];
      int mrow = (idx4 >> 5) % 9;      // element row (i*9+m) % 9 = m
      float idg = (mrow == 0) ? 1.f : ((mrow < 4) ? (1.f / 3.f) : 0.2f);
      v.x *= idg; v.y *= idg; v.z *= idg; v.w *= idg;
      dst[idx4] = v;
    }
    if (tid < 32) {
      int ii = tid >> 2, tj = tid & 3;
      int i = i0 + ii;
      int j = jbase + tj;
      float dx = pos[i * 3 + 0] - pj[tj][0];
      float dy = pos[i * 3 + 1] - pj[tj][1];
      float dz = pos[i * 3 + 2] - pj[tj][2];
      bool ok = (i != j) && (batch[i] == bj[tj]);
      float okf = ok ? 1.f : 0.f;
      float d2 = dx * dx + dy * dy + dz * dz;
      float dist = fmaxf(sqrtf(d2), 1e-8f);
      float inv = okf / dist;          // zeroes x,y,z (sh1..8) when invalid
      float x = dx * inv, y = dy * inv, z = dz * inv;
      wsm[ii][0][tj] = SH_C0 * okf;
      wsm[ii][1][tj] = SH_C1 * x;
      wsm[ii][2][tj] = SH_C1 * y;
      wsm[ii][3][tj] = SH_C1 * z;
      wsm[ii][4][tj] = SH_S15 * x * z;
      wsm[ii][5][tj] = SH_S15 * x * y;
      wsm[ii][6][tj] = SH_S5 * (y * y - 0.5f * (x * x + z * z));
      wsm[ii][7][tj] = SH_S15 * y * z;
      wsm[ii][8][tj] = 0.5f * SH_S15 * (z * z - x * x);
    }
    __syncthreads();
#pragma unroll
    for (int ii = 0; ii < 8; ++ii) {
#pragma unroll
      for (int m = 0; m < 9; ++m) {
        float2 w2 = *(const float2*)(&wsm[ii][m][jp * 2]);  // wave-broadcast
        float f = fs[ii][m][c];
        acc0 = fmaf(w2.x, f, acc0);
        acc1 = fmaf(w2.y, f, acc1);
      }
    }
    __syncthreads();
  }
  colm[(jbase + jp * 2 + 0) * 128 + c] = acc0 * (1.0f / 1024.0f);
  colm[(jbase + jp * 2 + 1) * 128 + c] = acc1 * (1.0f / 1024.0f);
}

// ---------------------------------------------------------------------------
// K4: q = rowmean @ q_w^T + q_b   (layout [i][c])
//     k = colmean @ k_w^T + k_b   (layout [h][j][d] for coalesced attn reads)
__global__ __launch_bounds__(128) void htr_qk(
    const float* __restrict__ rowm, const float* __restrict__ colm,
    const float* __restrict__ wT, const float* __restrict__ q_b,
    const float* __restrict__ k_b, float* __restrict__ qbuf,
    float* __restrict__ khbuf) {
  const int b = blockIdx.x;          // 0..2047
  const bool isq = b < 1024;
  const int i = isq ? b : (b - 1024);
  const float* src = isq ? (rowm + i * 128) : (colm + i * 128);
  const float* w = wT + (isq ? 0 : 16384);
  const int co = threadIdx.x;
  __shared__ float s[128];
  s[co] = src[co];
  __syncthreads();
  float acc = isq ? q_b[co] : k_b[co];
#pragma unroll 8
  for (int ci = 0; ci < 128; ++ci) acc = fmaf(s[ci], w[ci * 128 + co], acc);
  if (isq) qbuf[i * 128 + co] = acc;
  else khbuf[((co >> 4) * 1024 + i) * 16 + (co & 15)] = acc;
}

// ---------------------------------------------------------------------------
// K5: attn[h,i,:] = softmax over j of (q_ih . k_jh)/4, masked to same batch
// (diagonal INCLUDED — mask is `same`, not `valid`).
__global__ __launch_bounds__(256) void htr_attn(
    const float* __restrict__ qbuf, const float* __restrict__ khbuf,
    const int* __restrict__ batch, float* __restrict__ attn) {
  const int i = blockIdx.x;
  const int h = blockIdx.y;
  const int tid = threadIdx.x;
  __shared__ float qv[16];
  __shared__ float redm[4], reds[4];
  if (tid < 16) qv[tid] = qbuf[i * 128 + h * 16 + tid] * 0.25f;  // D^-0.5 folded
  __syncthreads();
  const int bi = batch[i];
  float l[4];
#pragma unroll
  for (int p = 0; p < 4; ++p) {
    int j = tid + (p << 8);
    float acc = -INFINITY;
    if (batch[j] == bi) {
      const float4* kp = (const float4*)(khbuf + (h * 1024 + j) * 16);
      float4 k0 = kp[0], k1 = kp[1], k2 = kp[2], k3 = kp[3];
      float d = 0.f;
      d = fmaf(qv[0], k0.x, d);  d = fmaf(qv[1], k0.y, d);
      d = fmaf(qv[2], k0.z, d);  d = fmaf(qv[3], k0.w, d);
      d = fmaf(qv[4], k1.x, d);  d = fmaf(qv[5], k1.y, d);
      d = fmaf(qv[6], k1.z, d);  d = fmaf(qv[7], k1.w, d);
      d = fmaf(qv[8], k2.x, d);  d = fmaf(qv[9], k2.y, d);
      d = fmaf(qv[10], k2.z, d); d = fmaf(qv[11], k2.w, d);
      d = fmaf(qv[12], k3.x, d); d = fmaf(qv[13], k3.y, d);
      d = fmaf(qv[14], k3.z, d); d = fmaf(qv[15], k3.w, d);
      acc = d;
    }
    l[p] = acc;
  }
  const int wave = tid >> 6, lane = tid & 63;
  float mx = fmaxf(fmaxf(l[0], l[1]), fmaxf(l[2], l[3]));
  mx = wave_max(mx);
  if (lane == 0) redm[wave] = mx;
  __syncthreads();
  const float M = fmaxf(fmaxf(redm[0], redm[1]), fmaxf(redm[2], redm[3]));
  float e[4];
  float ssum = 0.f;
#pragma unroll
  for (int p = 0; p < 4; ++p) { e[p] = expf(l[p] - M); ssum += e[p]; }
  ssum = wave_sum(ssum);
  if (lane == 0) reds[wave] = ssum;
  __syncthreads();
  const float inv = 1.0f / (reds[0] + reds[1] + reds[2] + reds[3]);
  float* dstp = attn + (h * 1024 + i) * 1024;
#pragma unroll
  for (int p = 0; p < 4; ++p) dstp[tid + (p << 8)] = e[p] * inv;
}

// ---------------------------------------------------------------------------
// K6: vbuf[j,m,:] = x_emb[j,m,:] @ v_w[l(m)]^T (+ v_b0 when m==0)
__global__ __launch_bounds__(128) void htr_vproj(
    const float* __restrict__ x_emb, const float* __restrict__ wT,
    const float* __restrict__ v_b0, float* __restrict__ vbuf) {
  const int bm = blockIdx.x;  // i*9+m
  const int m = bm % 9;
  const int l = (m == 0) ? 0 : ((m < 4) ? 1 : 2);
  const float* w = wT + (2 + l) * 16384;
  const int co = threadIdx.x;
  __shared__ float s[128];
  s[co] = x_emb[bm * 128 + co];
  __syncthreads();
  float acc = (m == 0) ? v_b0[co] : 0.f;
#pragma unroll 8
  for (int ci = 0; ci < 128; ++ci) acc = fmaf(s[ci], w[ci * 128 + co], acc);
  vbuf[bm * 128 + co] = acc;
}

// ---------------------------------------------------------------------------
// K7: o[i,m,c] = sum_j attn[h(c),i,j] * vbuf[j,m,c]
// block: 8 i's x (m-half: m 0..3 or 4..8). 256 threads = (ip 0..1) x (c).
template <int M0, int NM>
__device__ __forceinline__ void apply_body(
    const float* __restrict__ vbuf, const float* __restrict__ attn,
    float* __restrict__ obuf, int ibase, int tid) {
  __shared__ float vs[8][NM][128];
  __shared__ float ats[8][8][9];  // [h][ti][jj], jj-dim padded to 9
  const int ip = tid >> 7;
  const int c = tid & 127;
  const int h = c >> 4;
  float acc[4][NM];
#pragma unroll
  for (int r = 0; r < 4; ++r)
#pragma unroll
    for (int mm = 0; mm < NM; ++mm) acc[r][mm] = 0.f;

  for (int j0 = 0; j0 < 1024; j0 += 8) {
    float4* vdst = (float4*)(&vs[0][0][0]);
#pragma unroll
    for (int it = 0; it < NM; ++it) {
      int e4 = tid + it * 256;       // NM*256 float4 total
      int jj = e4 / (NM * 32);
      int rem = e4 - jj * (NM * 32);
      vdst[e4] = ((const float4*)(vbuf + (j0 + jj) * 1152 + M0 * 128))[rem];
    }
#pragma unroll
    for (int it = 0; it < 2; ++it) {
      int idx = tid + it * 256;      // 512 floats
      int hh = idx >> 6, ti = (idx >> 3) & 7, jj = idx & 7;
      ats[hh][ti][jj] = attn[(hh * 1024 + ibase + ti) * 1024 + j0 + jj];
    }
    __syncthreads();
#pragma unroll
    for (int jj = 0; jj < 8; ++jj) {
      float a0 = ats[h][ip * 4 + 0][jj];
      float a1 = ats[h][ip * 4 + 1][jj];
      float a2 = ats[h][ip * 4 + 2][jj];
      float a3 = ats[h][ip * 4 + 3][jj];
#pragma unroll
      for (int mm = 0; mm < NM; ++mm) {
        float v = vs[jj][mm][c];
        acc[0][mm] = fmaf(a0, v, acc[0][mm]);
        acc[1][mm] = fmaf(a1, v, acc[1][mm]);
        acc[2][mm] = fmaf(a2, v, acc[2][mm]);
        acc[3][mm] = fmaf(a3, v, acc[3][mm]);
      }
    }
    __syncthreads();
  }
#pragma unroll
  for (int r = 0; r < 4; ++r) {
    int i = ibase + ip * 4 + r;
#pragma unroll
    for (int mm = 0; mm < NM; ++mm)
      obuf[(i * 9 + M0 + mm) * 128 + c] = acc[r][mm];
  }
}

__global__ __launch_bounds__(256) void htr_apply(
    const float* __restrict__ vbuf, const float* __restrict__ attn,
    float* __restrict__ obuf) {
  const int ibase = blockIdx.x * 8;
  if (blockIdx.y == 0) apply_body<0, 4>(vbuf, attn, obuf, ibase, threadIdx.x);
  else apply_body<4, 5>(vbuf, attn, obuf, ibase, threadIdx.x);
}

// ---------------------------------------------------------------------------
// K8: out[i,m,:] = LayerNorm(x_emb[i,m,:] + obuf[i,m,:] @ out_w[l]^T)
__global__ __launch_bounds__(128) void htr_outln(
    const float* __restrict__ x_emb, const float* __restrict__ obuf,
    const float* __restrict__ wT, const float* __restrict__ ln_g,
    const float* __restrict__ ln_b, float* __restrict__ out) {
  const int bm = blockIdx.x;  // i*9+m
  const int m = bm % 9;
  const int l = (m == 0) ? 0 : ((m < 4) ? 1 : 2);
  const float* w = wT + (5 + l) * 16384;
  const int co = threadIdx.x;
  __shared__ float s[128];
  __shared__ float r1[2], r2[2];
  s[co] = obuf[bm * 128 + co];
  __syncthreads();
  float acc = 0.f;
#pragma unroll 8
  for (int ci = 0; ci < 128; ++ci) acc = fmaf(s[ci], w[ci * 128 + co], acc);
  float t = x_emb[bm * 128 + co] + acc;
  const int wave = co >> 6, lane = co & 63;
  float sv = wave_sum(t);
  float sq = wave_sum(t * t);
  if (lane == 0) { r1[wave] = sv; r2[wave] = sq; }
  __syncthreads();
  const float mu = (r1[0] + r1[1]) * (1.0f / 128.0f);
  const float ms = (r2[0] + r2[1]) * (1.0f / 128.0f);
  const float var = ms - mu * mu;
  out[bm * 128 + co] =
      (t - mu) * rsqrtf(var + 1e-5f) * ln_g[l * 128 + co] + ln_b[l * 128 + co];
}

// ---------------------------------------------------------------------------
extern "C" void kernel_launch(void* const* d_in, const int* in_sizes, int n_in,
                              void* d_out, int out_size, void* d_ws, size_t ws_size,
                              hipStream_t stream) {
  (void)in_sizes; (void)n_in; (void)out_size; (void)ws_size;
  const float* x_emb = (const float*)d_in[0];
  const float* pos   = (const float*)d_in[1];
  const float* q_w   = (const float*)d_in[2];
  const float* q_b   = (const float*)d_in[3];
  const float* k_w   = (const float*)d_in[4];
  const float* k_b   = (const float*)d_in[5];
  const float* v_w   = (const float*)d_in[6];
  const float* v_b0  = (const float*)d_in[7];
  const float* out_w = (const float*)d_in[8];
  const float* ln_g  = (const float*)d_in[9];
  const float* ln_b  = (const float*)d_in[10];
  const int*   batch = (const int*)d_in[11];
  float* out = (float*)d_out;

  // workspace layout (float offsets, total 11,419,648 floats = 45.7 MB)
  float* ws    = (float*)d_ws;
  float* S_row = ws;              //   9,216
  float* rowm  = ws + 16384;      // 131,072
  float* colm  = ws + 147456;     // 131,072
  float* qbuf  = ws + 278528;     // 131,072
  float* khbuf = ws + 409600;     // 131,072  [h][j][d]
  float* wT    = ws + 540672;     // 131,072  8 transposed 128x128 weights
  float* vbuf  = ws + 671744;     // 1,179,648
  float* obuf  = ws + 1851392;    // 1,179,648
  float* attn  = ws + 3031040;    // 8,388,608 [h][i][j]

  htr_transpose<<<8, 256, 0, stream>>>(q_w, k_w, v_w, out_w, wT);
  htr_row_stats<<<1024, 256, 0, stream>>>(pos, batch, S_row);
  htr_rowmean<<<1024, 128, 0, stream>>>(x_emb, S_row, rowm);
  htr_colmean<<<256, 256, 0, stream>>>(x_emb, pos, batch, colm);
  htr_qk<<<2048, 128, 0, stream>>>(rowm, colm, wT, q_b, k_b, qbuf, khbuf);
  htr_attn<<<dim3(1024, 8), 256, 0, stream>>>(qbuf, khbuf, batch, attn);
  htr_vproj<<<9216, 128, 0, stream>>>(x_emb, wT, v_b0, vbuf);
  htr_apply<<<dim3(128, 2), 256, 0, stream>>>(vbuf, attn, obuf);
  htr_outln<<<9216, 128, 0, stream>>>(x_emb, obuf, wT, ln_g, ln_b, out);
}

// Round 2
// 362.133 us; speedup vs baseline: 1.9786x; 1.9786x over previous
//
#include <hip/hip_runtime.h>
#include <math.h>

#define NN 1024

__device__ __forceinline__ float wave_sum(float v) {
#pragma unroll
  for (int off = 32; off > 0; off >>= 1) v += __shfl_down(v, off);
  return v;
}
__device__ __forceinline__ float wave_max(float v) {
#pragma unroll
  for (int off = 32; off > 0; off >>= 1) v = fmaxf(v, __shfl_down(v, off));
  return v;
}

#define SH_C0 0.28209479177387814f
#define SH_C1 0.4886025119029199f
#define SH_S15 1.0925484305920792f
#define SH_S5 0.6307831305050401f

// ---------------------------------------------------------------------------
// K0: transpose the 8 [128x128] weight matrices so GEMV reads are coalesced.
__global__ __launch_bounds__(256) void htr_transpose(
    const float* __restrict__ qw, const float* __restrict__ kw,
    const float* __restrict__ vw, const float* __restrict__ ow,
    float* __restrict__ wT) {
  const int b = blockIdx.x;  // 0..7
  const float* src;
  if (b == 0) src = qw;
  else if (b == 1) src = kw;
  else if (b < 5) src = vw + (b - 2) * 16384;
  else src = ow + (b - 5) * 16384;
  float* dst = wT + b * 16384;
  for (int idx = threadIdx.x; idx < 16384; idx += 256) {
    int r = idx >> 7, cc = idx & 127;
    dst[cc * 128 + r] = src[idx];
  }
}

// ---------------------------------------------------------------------------
// K1: S_row[i][m] = (1/N) sum_j valid(i,j) * sh_m(r_hat(i,j))
__global__ __launch_bounds__(256) void htr_row_stats(
    const float* __restrict__ pos, const int* __restrict__ batch,
    float* __restrict__ S_row) {
  const int i = blockIdx.x;
  const int tid = threadIdx.x;
  const float px = pos[i * 3 + 0], py = pos[i * 3 + 1], pz = pos[i * 3 + 2];
  const int bi = batch[i];
  float s[9];
#pragma unroll
  for (int m = 0; m < 9; ++m) s[m] = 0.f;
  for (int j = tid; j < NN; j += 256) {
    if (j == i) continue;
    if (batch[j] != bi) continue;
    float dx = px - pos[j * 3 + 0];
    float dy = py - pos[j * 3 + 1];
    float dz = pz - pos[j * 3 + 2];
    float d2 = dx * dx + dy * dy + dz * dz;
    float dist = fmaxf(sqrtf(d2), 1e-8f);
    float inv = 1.0f / dist;
    float x = dx * inv, y = dy * inv, z = dz * inv;
    s[0] += 1.0f;
    s[1] += x; s[2] += y; s[3] += z;
    s[4] += x * z; s[5] += x * y;
    s[6] += y * y - 0.5f * (x * x + z * z);
    s[7] += y * z;
    s[8] += z * z - x * x;
  }
  __shared__ float red[4][9];
  const int wave = tid >> 6, lane = tid & 63;
#pragma unroll
  for (int m = 0; m < 9; ++m) {
    float v = wave_sum(s[m]);
    if (lane == 0) red[wave][m] = v;
  }
  __syncthreads();
  if (tid < 9) {
    float v = red[0][tid] + red[1][tid] + red[2][tid] + red[3][tid];
    float scl = SH_S15;
    if (tid == 0) scl = SH_C0;
    else if (tid < 4) scl = SH_C1;
    else if (tid == 6) scl = SH_S5;
    else if (tid == 8) scl = 0.5f * SH_S15;
    S_row[i * 9 + tid] = v * scl * (1.0f / 1024.0f);
  }
}

// ---------------------------------------------------------------------------
// K2: rowmean[i,c] = sum_m S_row[i,m] * invdeg(m) * x_emb[i,m,c]
__global__ __launch_bounds__(128) void htr_rowmean(
    const float* __restrict__ x_emb, const float* __restrict__ S_row,
    float* __restrict__ rowm) {
  const int i = blockIdx.x;
  const int c = threadIdx.x;
  float acc = 0.f;
#pragma unroll
  for (int m = 0; m < 9; ++m) {
    float idg = (m == 0) ? 1.f : ((m < 4) ? (1.f / 3.f) : 0.2f);
    acc = fmaf(S_row[i * 9 + m] * idg, x_emb[(i * 9 + m) * 128 + c], acc);
  }
  rowm[i * 128 + c] = acc;
}

// ---------------------------------------------------------------------------
// K3: colmean partials. 8 j per block, i split 8 ways, 4-i LDS tiles.
// block 256 = jp(2, 4 j each) x c(128). LDS ~19.7 KB -> high occupancy.
// idg is folded into the sh weights (depends only on m).
#define CM_J 8
#define CM_TI 4
#define CM_ISPLIT 8
__global__ __launch_bounds__(256) void htr_colmean(
    const float* __restrict__ x_emb, const float* __restrict__ pos,
    const int* __restrict__ batch, float* __restrict__ part) {
  const int jbase = blockIdx.x * CM_J;
  const int tid = threadIdx.x;
  const int jp = tid >> 7;
  const int c = tid & 127;
  __shared__ __align__(16) float fs[CM_TI][9][128];     // 18.4 KB
  __shared__ __align__(16) float wsm[CM_TI][9][CM_J];   // 1.15 KB
  __shared__ float pj[CM_J][3];
  __shared__ int bj[CM_J];
  if (tid < CM_J) {
    int j = jbase + tid;
    pj[tid][0] = pos[j * 3 + 0];
    pj[tid][1] = pos[j * 3 + 1];
    pj[tid][2] = pos[j * 3 + 2];
    bj[tid] = batch[j];
  }
  __syncthreads();
  float acc[4] = {0.f, 0.f, 0.f, 0.f};
  const int i_begin = blockIdx.y * (1024 / CM_ISPLIT);
  for (int i0 = i_begin; i0 < i_begin + (1024 / CM_ISPLIT); i0 += CM_TI) {
    // stage f tile: CM_TI*9*128 = 4608 floats = 2304 float2, 9 per thread
    const float2* src = (const float2*)(x_emb + i0 * 1152);
    float2* dst = (float2*)(&fs[0][0][0]);
#pragma unroll
    for (int it = 0; it < 9; ++it) dst[tid + it * 256] = src[tid + it * 256];
    // sh weights for CM_TI x CM_J pairs (idg folded in)
    if (tid < CM_TI * CM_J) {
      int ii = tid >> 3, tj = tid & 7;
      int i = i0 + ii;
      int j = jbase + tj;
      float dx = pos[i * 3 + 0] - pj[tj][0];
      float dy = pos[i * 3 + 1] - pj[tj][1];
      float dz = pos[i * 3 + 2] - pj[tj][2];
      bool ok = (i != j) && (batch[i] == bj[tj]);
      float okf = ok ? 1.f : 0.f;
      float d2 = dx * dx + dy * dy + dz * dz;
      float inv = okf / fmaxf(sqrtf(d2), 1e-8f);
      float x = dx * inv, y = dy * inv, z = dz * inv;
      wsm[ii][0][tj] = SH_C0 * okf;
      wsm[ii][1][tj] = (SH_C1 * (1.f / 3.f)) * x;
      wsm[ii][2][tj] = (SH_C1 * (1.f / 3.f)) * y;
      wsm[ii][3][tj] = (SH_C1 * (1.f / 3.f)) * z;
      wsm[ii][4][tj] = (SH_S15 * 0.2f) * x * z;
      wsm[ii][5][tj] = (SH_S15 * 0.2f) * x * y;
      wsm[ii][6][tj] = (SH_S5 * 0.2f) * (y * y - 0.5f * (x * x + z * z));
      wsm[ii][7][tj] = (SH_S15 * 0.2f) * y * z;
      wsm[ii][8][tj] = (0.5f * SH_S15 * 0.2f) * (z * z - x * x);
    }
    __syncthreads();
#pragma unroll
    for (int ii = 0; ii < CM_TI; ++ii) {
#pragma unroll
      for (int m = 0; m < 9; ++m) {
        float4 w4 = *(const float4*)(&wsm[ii][m][jp * 4]);  // broadcast
        float f = fs[ii][m][c];
        acc[0] = fmaf(w4.x, f, acc[0]);
        acc[1] = fmaf(w4.y, f, acc[1]);
        acc[2] = fmaf(w4.z, f, acc[2]);
        acc[3] = fmaf(w4.w, f, acc[3]);
      }
    }
    __syncthreads();
  }
#pragma unroll
  for (int r = 0; r < 4; ++r)
    part[(blockIdx.y * 1024 + jbase + jp * 4 + r) * 128 + c] = acc[r];
}

// ---------------------------------------------------------------------------
// K3b: generic slice reduction: dst[t] = scale * sum_s src[s*n + t]
__global__ __launch_bounds__(256) void htr_reduce(
    const float* __restrict__ src, float* __restrict__ dst, int n, int nsl,
    float scale) {
  int t = blockIdx.x * 256 + threadIdx.x;
  if (t >= n) return;
  float a = 0.f;
  for (int s = 0; s < nsl; ++s) a += src[s * n + t];
  dst[t] = a * scale;
}

// ---------------------------------------------------------------------------
// K4: q = rowmean @ q_w^T + q_b   (layout [i][c])
//     k = colmean @ k_w^T + k_b   (layout [h][j][d])
__global__ __launch_bounds__(128) void htr_qk(
    const float* __restrict__ rowm, const float* __restrict__ colm,
    const float* __restrict__ wT, const float* __restrict__ q_b,
    const float* __restrict__ k_b, float* __restrict__ qbuf,
    float* __restrict__ khbuf) {
  const int b = blockIdx.x;
  const bool isq = b < 1024;
  const int i = isq ? b : (b - 1024);
  const float* src = isq ? (rowm + i * 128) : (colm + i * 128);
  const float* w = wT + (isq ? 0 : 16384);
  const int co = threadIdx.x;
  __shared__ float s[128];
  s[co] = src[co];
  __syncthreads();
  float acc = isq ? q_b[co] : k_b[co];
#pragma unroll 8
  for (int ci = 0; ci < 128; ++ci) acc = fmaf(s[ci], w[ci * 128 + co], acc);
  if (isq) qbuf[i * 128 + co] = acc;
  else khbuf[((co >> 4) * 1024 + i) * 16 + (co & 15)] = acc;
}

// ---------------------------------------------------------------------------
// K5: attn[h,i,:] = softmax_j (q_ih . k_jh)/4, masked to same batch.
__global__ __launch_bounds__(256) void htr_attn(
    const float* __restrict__ qbuf, const float* __restrict__ khbuf,
    const int* __restrict__ batch, float* __restrict__ attn) {
  const int i = blockIdx.x;
  const int h = blockIdx.y;
  const int tid = threadIdx.x;
  __shared__ float qv[16];
  __shared__ float redm[4], reds[4];
  if (tid < 16) qv[tid] = qbuf[i * 128 + h * 16 + tid] * 0.25f;
  __syncthreads();
  const int bi = batch[i];
  float l[4];
#pragma unroll
  for (int p = 0; p < 4; ++p) {
    int j = tid + (p << 8);
    float acc = -INFINITY;
    if (batch[j] == bi) {
      const float4* kp = (const float4*)(khbuf + (h * 1024 + j) * 16);
      float4 k0 = kp[0], k1 = kp[1], k2 = kp[2], k3 = kp[3];
      float d = 0.f;
      d = fmaf(qv[0], k0.x, d);  d = fmaf(qv[1], k0.y, d);
      d = fmaf(qv[2], k0.z, d);  d = fmaf(qv[3], k0.w, d);
      d = fmaf(qv[4], k1.x, d);  d = fmaf(qv[5], k1.y, d);
      d = fmaf(qv[6], k1.z, d);  d = fmaf(qv[7], k1.w, d);
      d = fmaf(qv[8], k2.x, d);  d = fmaf(qv[9], k2.y, d);
      d = fmaf(qv[10], k2.z, d); d = fmaf(qv[11], k2.w, d);
      d = fmaf(qv[12], k3.x, d); d = fmaf(qv[13], k3.y, d);
      d = fmaf(qv[14], k3.z, d); d = fmaf(qv[15], k3.w, d);
      acc = d;
    }
    l[p] = acc;
  }
  const int wave = tid >> 6, lane = tid & 63;
  float mx = fmaxf(fmaxf(l[0], l[1]), fmaxf(l[2], l[3]));
  mx = wave_max(mx);
  if (lane == 0) redm[wave] = mx;
  __syncthreads();
  const float M = fmaxf(fmaxf(redm[0], redm[1]), fmaxf(redm[2], redm[3]));
  float e[4];
  float ssum = 0.f;
#pragma unroll
  for (int p = 0; p < 4; ++p) { e[p] = expf(l[p] - M); ssum += e[p]; }
  ssum = wave_sum(ssum);
  if (lane == 0) reds[wave] = ssum;
  __syncthreads();
  const float inv = 1.0f / (reds[0] + reds[1] + reds[2] + reds[3]);
  float* dstp = attn + (h * 1024 + i) * 1024;
#pragma unroll
  for (int p = 0; p < 4; ++p) dstp[tid + (p << 8)] = e[p] * inv;
}

// ---------------------------------------------------------------------------
// K6: vbuf[j,m,:] = x_emb[j,m,:] @ v_w[l(m)]^T (+ v_b0 when m==0)
__global__ __launch_bounds__(128) void htr_vproj(
    const float* __restrict__ x_emb, const float* __restrict__ wT,
    const float* __restrict__ v_b0, float* __restrict__ vbuf) {
  const int bm = blockIdx.x;  // i*9+m
  const int m = bm % 9;
  const int l = (m == 0) ? 0 : ((m < 4) ? 1 : 2);
  const float* w = wT + (2 + l) * 16384;
  const int co = threadIdx.x;
  __shared__ float s[128];
  s[co] = x_emb[bm * 128 + co];
  __syncthreads();
  float acc = (m == 0) ? v_b0[co] : 0.f;
#pragma unroll 8
  for (int ci = 0; ci < 128; ++ci) acc = fmaf(s[ci], w[ci * 128 + co], acc);
  vbuf[bm * 128 + co] = acc;
}

// ---------------------------------------------------------------------------
// K7: o[i,m,c] = sum_j attn[h(c),i,j] * vbuf[j,m,c]
// grid (iblk=128, mhalf=2, jsplit=4); atomicAdd into zeroed obuf.
template <int M0, int NM>
__device__ __forceinline__ void apply_body(
    const float* __restrict__ vbuf, const float* __restrict__ attn,
    float* __restrict__ obuf, int ibase, int j_begin, int tid) {
  __shared__ float vs[8][NM][128];
  __shared__ float ats[8][8][9];  // [h][ti][jj], padded
  const int ip = tid >> 7;
  const int c = tid & 127;
  const int h = c >> 4;
  float acc[4][NM];
#pragma unroll
  for (int r = 0; r < 4; ++r)
#pragma unroll
    for (int mm = 0; mm < NM; ++mm) acc[r][mm] = 0.f;

  for (int j0 = j_begin; j0 < j_begin + 256; j0 += 8) {
    float4* vdst = (float4*)(&vs[0][0][0]);
#pragma unroll
    for (int it = 0; it < NM; ++it) {
      int e4 = tid + it * 256;
      int jj = e4 / (NM * 32);
      int rem = e4 - jj * (NM * 32);
      vdst[e4] = ((const float4*)(vbuf + (j0 + jj) * 1152 + M0 * 128))[rem];
    }
#pragma unroll
    for (int it = 0; it < 2; ++it) {
      int idx = tid + it * 256;
      int hh = idx >> 6, ti = (idx >> 3) & 7, jj = idx & 7;
      ats[hh][ti][jj] = attn[(hh * 1024 + ibase + ti) * 1024 + j0 + jj];
    }
    __syncthreads();
#pragma unroll
    for (int jj = 0; jj < 8; ++jj) {
      float a0 = ats[h][ip * 4 + 0][jj];
      float a1 = ats[h][ip * 4 + 1][jj];
      float a2 = ats[h][ip * 4 + 2][jj];
      float a3 = ats[h][ip * 4 + 3][jj];
#pragma unroll
      for (int mm = 0; mm < NM; ++mm) {
        float v = vs[jj][mm][c];
        acc[0][mm] = fmaf(a0, v, acc[0][mm]);
        acc[1][mm] = fmaf(a1, v, acc[1][mm]);
        acc[2][mm] = fmaf(a2, v, acc[2][mm]);
        acc[3][mm] = fmaf(a3, v, acc[3][mm]);
      }
    }
    __syncthreads();
  }
#pragma unroll
  for (int r = 0; r < 4; ++r) {
    int i = ibase + ip * 4 + r;
#pragma unroll
    for (int mm = 0; mm < NM; ++mm)
      atomicAdd(&obuf[(i * 9 + M0 + mm) * 128 + c], acc[r][mm]);
  }
}

__global__ __launch_bounds__(256) void htr_apply(
    const float* __restrict__ vbuf, const float* __restrict__ attn,
    float* __restrict__ obuf) {
  const int ibase = blockIdx.x * 8;
  const int j_begin = blockIdx.z * 256;
  if (blockIdx.y == 0)
    apply_body<0, 4>(vbuf, attn, obuf, ibase, j_begin, threadIdx.x);
  else
    apply_body<4, 5>(vbuf, attn, obuf, ibase, j_begin, threadIdx.x);
}

// ---------------------------------------------------------------------------
// K8: out[i,m,:] = LayerNorm(x_emb[i,m,:] + obuf[i,m,:] @ out_w[l]^T)
__global__ __launch_bounds__(128) void htr_outln(
    const float* __restrict__ x_emb, const float* __restrict__ obuf,
    const float* __restrict__ wT, const float* __restrict__ ln_g,
    const float* __restrict__ ln_b, float* __restrict__ out) {
  const int bm = blockIdx.x;  // i*9+m
  const int m = bm % 9;
  const int l = (m == 0) ? 0 : ((m < 4) ? 1 : 2);
  const float* w = wT + (5 + l) * 16384;
  const int co = threadIdx.x;
  __shared__ float s[128];
  __shared__ float r1[2], r2[2];
  s[co] = obuf[bm * 128 + co];
  __syncthreads();
  float acc = 0.f;
#pragma unroll 8
  for (int ci = 0; ci < 128; ++ci) acc = fmaf(s[ci], w[ci * 128 + co], acc);
  float t = x_emb[bm * 128 + co] + acc;
  const int wave = co >> 6, lane = co & 63;
  float sv = wave_sum(t);
  float sq = wave_sum(t * t);
  if (lane == 0) { r1[wave] = sv; r2[wave] = sq; }
  __syncthreads();
  const float mu = (r1[0] + r1[1]) * (1.0f / 128.0f);
  const float ms = (r2[0] + r2[1]) * (1.0f / 128.0f);
  const float var = ms - mu * mu;
  out[bm * 128 + co] =
      (t - mu) * rsqrtf(var + 1e-5f) * ln_g[l * 128 + co] + ln_b[l * 128 + co];
}

// ---------------------------------------------------------------------------
extern "C" void kernel_launch(void* const* d_in, const int* in_sizes, int n_in,
                              void* d_out, int out_size, void* d_ws, size_t ws_size,
                              hipStream_t stream) {
  (void)in_sizes; (void)n_in; (void)out_size; (void)ws_size;
  const float* x_emb = (const float*)d_in[0];
  const float* pos   = (const float*)d_in[1];
  const float* q_w   = (const float*)d_in[2];
  const float* q_b   = (const float*)d_in[3];
  const float* k_w   = (const float*)d_in[4];
  const float* k_b   = (const float*)d_in[5];
  const float* v_w   = (const float*)d_in[6];
  const float* v_b0  = (const float*)d_in[7];
  const float* out_w = (const float*)d_in[8];
  const float* ln_g  = (const float*)d_in[9];
  const float* ln_b  = (const float*)d_in[10];
  const int*   batch = (const int*)d_in[11];
  float* out = (float*)d_out;

  // workspace layout (float offsets, total 11,419,648 floats = 45.7 MB)
  float* ws    = (float*)d_ws;
  float* S_row = ws;              //   9,216
  float* rowm  = ws + 16384;      // 131,072
  float* colm  = ws + 147456;     // 131,072
  float* qbuf  = ws + 278528;     // 131,072
  float* khbuf = ws + 409600;     // 131,072  [h][j][d]
  float* wT    = ws + 540672;     // 131,072
  float* vbuf  = ws + 671744;     // 1,179,648
  float* obuf  = ws + 1851392;    // 1,179,648
  float* attn  = ws + 3031040;    // 8,388,608 [h][i][j]
  float* part  = attn;            // colmean partials (1,048,576) alias attn
                                  // (attn written only after reduce)

  htr_transpose<<<8, 256, 0, stream>>>(q_w, k_w, v_w, out_w, wT);
  htr_row_stats<<<1024, 256, 0, stream>>>(pos, batch, S_row);
  htr_rowmean<<<1024, 128, 0, stream>>>(x_emb, S_row, rowm);
  htr_colmean<<<dim3(1024 / CM_J, CM_ISPLIT), 256, 0, stream>>>(x_emb, pos,
                                                                batch, part);
  htr_reduce<<<512, 256, 0, stream>>>(part, colm, 131072, CM_ISPLIT,
                                      1.0f / 1024.0f);
  htr_qk<<<2048, 128, 0, stream>>>(rowm, colm, wT, q_b, k_b, qbuf, khbuf);
  htr_attn<<<dim3(1024, 8), 256, 0, stream>>>(qbuf, khbuf, batch, attn);
  htr_vproj<<<9216, 128, 0, stream>>>(x_emb, wT, v_b0, vbuf);
  hipMemsetAsync(obuf, 0, 1179648 * sizeof(float), stream);
  htr_apply<<<dim3(128, 2, 4), 256, 0, stream>>>(vbuf, attn, obuf);
  htr_outln<<<9216, 128, 0, stream>>>(x_emb, obuf, wT, ln_g, ln_b, out);
}